// Round 1
// baseline (148.831 us; speedup 1.0000x reference)
//
#include <hip/hip_runtime.h>
#include <hip/hip_bf16.h>

#define DI __device__ __forceinline__

typedef __bf16 bf16x8 __attribute__((ext_vector_type(8)));
typedef float f32x4 __attribute__((ext_vector_type(4)));

DI unsigned short f2bf(float f) {
    unsigned u = __builtin_bit_cast(unsigned, f);
    u += 0x7fffu + ((u >> 16) & 1u);   // RNE
    return (unsigned short)(u >> 16);
}

// swizzled LDS byte offset for [row][16B-slot ks] tiles with 64B rows
DI int swz(int row, int ks) { return row * 64 + ((ks ^ ((row >> 1) & 3)) << 4); }

// ---------------- GroupNorm: x[b,512,1024] f32 -> h[b,512,1024] bf16 --------
__global__ __launch_bounds__(256) void gn_kernel(const float* __restrict__ x,
                                                 const float* __restrict__ gs,
                                                 const float* __restrict__ gb,
                                                 unsigned short* __restrict__ h) {
    int b = blockIdx.x >> 3, g = blockIdx.x & 7;
    size_t base = ((size_t)b * 512 + (size_t)g * 64) * 1024;
    const float4* xp = (const float4*)(x + base);
    int t = threadIdx.x;
    float s = 0.f, q = 0.f;
    for (int it = 0; it < 64; ++it) {
        float4 v = xp[it * 256 + t];
        s += (v.x + v.y) + (v.z + v.w);
        q += (v.x * v.x + v.y * v.y) + (v.z * v.z + v.w * v.w);
    }
#pragma unroll
    for (int o = 32; o; o >>= 1) { s += __shfl_xor(s, o); q += __shfl_xor(q, o); }
    __shared__ float rs[4], rq[4];
    int lane = t & 63, wid = t >> 6;
    if (!lane) { rs[wid] = s; rq[wid] = q; }
    __syncthreads();
    s = rs[0] + rs[1] + rs[2] + rs[3];
    q = rq[0] + rq[1] + rq[2] + rq[3];
    float mean = s * (1.f / 65536.f);
    float var = q * (1.f / 65536.f) - mean * mean;
    float rstd = rsqrtf(var + 1e-5f);
    unsigned short* hp = h + base;
    for (int it = 0; it < 64; ++it) {
        int idx = it * 256 + t;
        float4 v = xp[idx];
        int c = g * 64 + (idx >> 8);
        float sc = gs[c] * rstd;
        float bi = gb[c] - mean * sc;
        ushort4 o;
        o.x = f2bf(v.x * sc + bi); o.y = f2bf(v.y * sc + bi);
        o.z = f2bf(v.z * sc + bi); o.w = f2bf(v.w * sc + bi);
        ((ushort4*)hp)[idx] = o;
    }
}

// ------------- transpose: in[b,512,1024] bf16 -> out[b,1024,512] bf16 -------
__global__ __launch_bounds__(256) void transpose_kernel(const unsigned short* __restrict__ in,
                                                        unsigned short* __restrict__ outp) {
    __shared__ unsigned short tile[64][65];
    int i0 = blockIdx.x * 64;
    int c0 = blockIdx.y * 64;
    size_t bb = (size_t)blockIdx.z * 512 * 1024;
    int t = threadIdx.x;
    int r = t >> 3;
    int col0 = (t & 7) * 8;
#pragma unroll
    for (int p = 0; p < 2; ++p) {
        int row = r + p * 32;
        uint4 v = *(const uint4*)&in[bb + (size_t)(c0 + row) * 1024 + i0 + col0];
        const unsigned short* pv = (const unsigned short*)&v;
#pragma unroll
        for (int j = 0; j < 8; ++j) tile[row][col0 + j] = pv[j];
    }
    __syncthreads();
    size_t ob = (size_t)blockIdx.z * 1024 * 512;
#pragma unroll
    for (int p = 0; p < 2; ++p) {
        int row = r + p * 32;
        unsigned short v[8];
#pragma unroll
        for (int j = 0; j < 8; ++j) v[j] = tile[col0 + j][row];
        *(uint4*)&outp[ob + (size_t)(i0 + row) * 512 + c0 + col0] = *(const uint4*)v;
    }
}

// ------------- weights f32 -> bf16 (4 matrices of 512x512) ------------------
__global__ __launch_bounds__(256) void wcvt_kernel(const float* __restrict__ w0,
                                                   const float* __restrict__ w1,
                                                   const float* __restrict__ w2,
                                                   const float* __restrict__ w3,
                                                   unsigned short* __restrict__ outp) {
    const float* s = (blockIdx.y == 0) ? w0 : (blockIdx.y == 1) ? w1 : (blockIdx.y == 2) ? w2 : w3;
    unsigned short* o = outp + (size_t)blockIdx.y * 262144;
    int idx = blockIdx.x * 256 + threadIdx.x;   // float4 index, 65536 total
    float4 v = ((const float4*)s)[idx];
    ushort4 r;
    r.x = f2bf(v.x); r.y = f2bf(v.y); r.z = f2bf(v.z); r.w = f2bf(v.w);
    ((ushort4*)o)[idx] = r;
}

// ------------- generic GEMM: C[M,N] = A[M,K] * B[N,K]^T  --------------------
// OUT: 0 = bf16 natural [M][N]; 1 = bf16 transposed [N][M]; 2 = f32 natural
template <int OUT, bool BIAS, bool RES>
__global__ __launch_bounds__(256) void gemm_bt(const unsigned short* __restrict__ A,
                                               const unsigned short* __restrict__ B,
                                               const float* __restrict__ bias,
                                               void* __restrict__ Cv,
                                               const float* __restrict__ resid,
                                               int M, int N, int K, float scale,
                                               size_t sA, size_t sB, size_t sC) {
    __shared__ __align__(16) unsigned short As[4096];   // 128 x 32 bf16 (swizzled)
    __shared__ __align__(16) unsigned short Bs[4096];
    int b = blockIdx.y;
    const unsigned short* Ab = A + sA * b;
    const unsigned short* Bb = B + sB * b;
    int nTx = N >> 7;
    int tx = blockIdx.x % nTx, ty = blockIdx.x / nTx;
    int m0 = ty << 7, n0 = tx << 7;
    int t = threadIdx.x;
    int lane = t & 63, wid = t >> 6;
    int wm = (wid >> 1) * 64, wn = (wid & 1) * 64;

    f32x4 acc[4][4];
#pragma unroll
    for (int i = 0; i < 4; ++i)
#pragma unroll
        for (int j = 0; j < 4; ++j) acc[i][j] = (f32x4){0.f, 0.f, 0.f, 0.f};

    int srow = t >> 2, sks = t & 3;
    int wofs0 = swz(srow, sks), wofs1 = swz(srow + 64, sks);
    const int l15 = lane & 15, lks = lane >> 4;

    for (int k0 = 0; k0 < K; k0 += 32) {
        uint4 a0 = *(const uint4*)&Ab[(size_t)(m0 + srow) * K + k0 + sks * 8];
        uint4 a1 = *(const uint4*)&Ab[(size_t)(m0 + srow + 64) * K + k0 + sks * 8];
        uint4 b0 = *(const uint4*)&Bb[(size_t)(n0 + srow) * K + k0 + sks * 8];
        uint4 b1 = *(const uint4*)&Bb[(size_t)(n0 + srow + 64) * K + k0 + sks * 8];
        __syncthreads();
        *(uint4*)((char*)As + wofs0) = a0;
        *(uint4*)((char*)As + wofs1) = a1;
        *(uint4*)((char*)Bs + wofs0) = b0;
        *(uint4*)((char*)Bs + wofs1) = b1;
        __syncthreads();
        bf16x8 af[4], bfr[4];
#pragma unroll
        for (int m = 0; m < 4; ++m)
            af[m] = *(const bf16x8*)((const char*)As + swz(wm + m * 16 + l15, lks));
#pragma unroll
        for (int n = 0; n < 4; ++n)
            bfr[n] = *(const bf16x8*)((const char*)Bs + swz(wn + n * 16 + l15, lks));
#pragma unroll
        for (int m = 0; m < 4; ++m)
#pragma unroll
            for (int n = 0; n < 4; ++n)
                acc[m][n] = __builtin_amdgcn_mfma_f32_16x16x32_bf16(af[m], bfr[n], acc[m][n], 0, 0, 0);
    }

    const int rbase = (lane >> 4) * 4;
    const size_t cb = sC * b;
#pragma unroll
    for (int m = 0; m < 4; ++m) {
        const int mg0 = m0 + wm + m * 16 + rbase;
        float bv[4];
#pragma unroll
        for (int j = 0; j < 4; ++j) bv[j] = BIAS ? bias[mg0 + j] : 0.f;
#pragma unroll
        for (int n = 0; n < 4; ++n) {
            const int ng = n0 + wn + n * 16 + l15;
            f32x4 v = acc[m][n];
            if constexpr (OUT == 1) {
                unsigned short* Ct = (unsigned short*)Cv + cb;
                ushort4 o;
                o.x = f2bf(v[0] * scale + bv[0]);
                o.y = f2bf(v[1] * scale + bv[1]);
                o.z = f2bf(v[2] * scale + bv[2]);
                o.w = f2bf(v[3] * scale + bv[3]);
                *(ushort4*)&Ct[(size_t)ng * M + mg0] = o;
            } else if constexpr (OUT == 0) {
                unsigned short* Cb = (unsigned short*)Cv + cb;
#pragma unroll
                for (int j = 0; j < 4; ++j)
                    Cb[(size_t)(mg0 + j) * N + ng] = f2bf(v[j] * scale + bv[j]);
            } else {
                float* Cf = (float*)Cv + cb;
#pragma unroll
                for (int j = 0; j < 4; ++j) {
                    float r = v[j] * scale + bv[j];
                    if constexpr (RES) r += resid[cb + (size_t)(mg0 + j) * N + ng];
                    Cf[(size_t)(mg0 + j) * N + ng] = r;
                }
            }
        }
    }
}

// ------------- row softmax: S[8192,1024] f32 -> P bf16 ----------------------
__global__ __launch_bounds__(256) void softmax_kernel(const float* __restrict__ S,
                                                      unsigned short* __restrict__ P) {
    size_t row = blockIdx.x;
    const float4* sp = (const float4*)(S + row * 1024);
    int t = threadIdx.x;
    float4 v = sp[t];
    float m = fmaxf(fmaxf(v.x, v.y), fmaxf(v.z, v.w));
#pragma unroll
    for (int o = 32; o; o >>= 1) m = fmaxf(m, __shfl_xor(m, o));
    __shared__ float rm[4], rs[4];
    int lane = t & 63, wid = t >> 6;
    if (!lane) rm[wid] = m;
    __syncthreads();
    m = fmaxf(fmaxf(rm[0], rm[1]), fmaxf(rm[2], rm[3]));
    float e0 = __expf(v.x - m), e1 = __expf(v.y - m);
    float e2 = __expf(v.z - m), e3 = __expf(v.w - m);
    float s = (e0 + e1) + (e2 + e3);
#pragma unroll
    for (int o = 32; o; o >>= 1) s += __shfl_xor(s, o);
    if (!lane) rs[wid] = s;
    __syncthreads();
    s = rs[0] + rs[1] + rs[2] + rs[3];
    float inv = 1.f / s;
    ushort4 o4;
    o4.x = f2bf(e0 * inv); o4.y = f2bf(e1 * inv);
    o4.z = f2bf(e2 * inv); o4.w = f2bf(e3 * inv);
    ((ushort4*)(P + row * 1024))[t] = o4;
}

extern "C" void kernel_launch(void* const* d_in, const int* in_sizes, int n_in,
                              void* d_out, int out_size, void* d_ws, size_t ws_size,
                              hipStream_t stream) {
    const float* x  = (const float*)d_in[0];
    const float* gs = (const float*)d_in[1];
    const float* gb = (const float*)d_in[2];
    const float* wq = (const float*)d_in[3];
    const float* bq = (const float*)d_in[4];
    const float* wk = (const float*)d_in[5];
    const float* bk = (const float*)d_in[6];
    const float* wv = (const float*)d_in[7];
    const float* bv = (const float*)d_in[8];
    const float* wp = (const float*)d_in[9];
    const float* bp = (const float*)d_in[10];
    float* out = (float*)d_out;

    char* ws = (char*)d_ws;
    const size_t MB = 1u << 20;
    unsigned short* hT  = (unsigned short*)(ws + 0);        // [b][1024][512] bf16, 8MB
    unsigned short* wb  = (unsigned short*)(ws + 8 * MB);   // 4x 512x512 bf16, 2MB
    unsigned short* qT  = (unsigned short*)(ws + 10 * MB);  // [b][1024][512]
    unsigned short* kT  = (unsigned short*)(ws + 18 * MB);  // [b][1024][512]
    unsigned short* vN  = (unsigned short*)(ws + 26 * MB);  // [b][512][1024]
    float*          Sf  = (float*)(ws + 34 * MB);           // [b][1024][1024] f32, 32MB
    unsigned short* P   = (unsigned short*)(ws + 66 * MB);  // [b][1024][1024] bf16, 16MB
    unsigned short* OT  = (unsigned short*)(ws + 82 * MB);  // [b][1024][512]
    unsigned short* hN  = (unsigned short*)(ws + 34 * MB);  // alias S (dead before S)

    const unsigned short* wqb = wb;
    const unsigned short* wkb = wb + 262144;
    const unsigned short* wvb = wb + 2 * 262144;
    const unsigned short* wpb = wb + 3 * 262144;

    // 1. GroupNorm -> h natural bf16
    gn_kernel<<<64, 256, 0, stream>>>(x, gs, gb, hN);
    // 2. transpose -> hT
    transpose_kernel<<<dim3(16, 8, 8), 256, 0, stream>>>(hN, hT);
    // 3. weights -> bf16
    wcvt_kernel<<<dim3(256, 4), 256, 0, stream>>>(wq, wk, wv, wp, wb);

    const size_t sH = 1024 * 512;     // hT / qT / kT / OT per-batch elems
    const size_t sV = 512 * 1024;
    const size_t sS = 1024 * 1024;

    // 4. Q = Wq*H (+bq), write transposed [i][c]
    gemm_bt<1, true, false><<<dim3(32, 8), 256, 0, stream>>>(
        wqb, hT, bq, qT, nullptr, 512, 1024, 512, 1.f, 0, sH, sH);
    // 5. K
    gemm_bt<1, true, false><<<dim3(32, 8), 256, 0, stream>>>(
        wkb, hT, bk, kT, nullptr, 512, 1024, 512, 1.f, 0, sH, sH);
    // 6. V natural [c][i]
    gemm_bt<0, true, false><<<dim3(32, 8), 256, 0, stream>>>(
        wvb, hT, bv, vN, nullptr, 512, 1024, 512, 1.f, 0, sH, sV);
    // 7. S = qT * kT^T * scale, f32
    gemm_bt<2, false, false><<<dim3(64, 8), 256, 0, stream>>>(
        qT, kT, nullptr, Sf, nullptr, 1024, 1024, 512, 0.044194173824159216f, sH, sH, sS);
    // 8. softmax rows -> P bf16
    softmax_kernel<<<8192, 256, 0, stream>>>(Sf, P);
    // 9. O = V * P^T, write transposed -> OT[i][c]
    gemm_bt<1, false, false><<<dim3(32, 8), 256, 0, stream>>>(
        vN, P, nullptr, OT, nullptr, 512, 1024, 1024, 1.f, sV, sS, sH);
    // 10. out = Wp*O + bp + x, f32
    gemm_bt<2, true, true><<<dim3(32, 8), 256, 0, stream>>>(
        wpb, OT, bp, out, x, 512, 1024, 512, 1.f, 0, sH, sV);
}

// Round 2
// 104.145 us; speedup vs baseline: 1.4291x; 1.4291x over previous
//
#include <hip/hip_runtime.h>
#include <hip/hip_bf16.h>

#define DI __device__ __forceinline__

typedef __bf16 bf16x8 __attribute__((ext_vector_type(8)));
typedef float f32x4 __attribute__((ext_vector_type(4)));

typedef const void __attribute__((address_space(1))) gas_t;
typedef void __attribute__((address_space(3))) las_t;

DI unsigned short f2bf(float f) {
    unsigned u = __builtin_bit_cast(unsigned, f);
    u += 0x7fffu + ((u >> 16) & 1u);   // RNE
    return (unsigned short)(u >> 16);
}
DI float bf2f(unsigned short s) {
    return __builtin_bit_cast(float, (unsigned)s << 16);
}

// ---------------- GroupNorm: x[b,512,1024] f32 -> h[b,512,1024] bf16 --------
__global__ __launch_bounds__(256) void gn_kernel(const float* __restrict__ x,
                                                 const float* __restrict__ gs,
                                                 const float* __restrict__ gb,
                                                 unsigned short* __restrict__ h) {
    int b = blockIdx.x >> 3, g = blockIdx.x & 7;
    size_t base = ((size_t)b * 512 + (size_t)g * 64) * 1024;
    const float4* xp = (const float4*)(x + base);
    int t = threadIdx.x;
    float s = 0.f, q = 0.f;
    for (int it = 0; it < 64; ++it) {
        float4 v = xp[it * 256 + t];
        s += (v.x + v.y) + (v.z + v.w);
        q += (v.x * v.x + v.y * v.y) + (v.z * v.z + v.w * v.w);
    }
#pragma unroll
    for (int o = 32; o; o >>= 1) { s += __shfl_xor(s, o); q += __shfl_xor(q, o); }
    __shared__ float rs[4], rq[4];
    int lane = t & 63, wid = t >> 6;
    if (!lane) { rs[wid] = s; rq[wid] = q; }
    __syncthreads();
    s = rs[0] + rs[1] + rs[2] + rs[3];
    q = rq[0] + rq[1] + rq[2] + rq[3];
    float mean = s * (1.f / 65536.f);
    float var = q * (1.f / 65536.f) - mean * mean;
    float rstd = rsqrtf(var + 1e-5f);
    unsigned short* hp = h + base;
    for (int it = 0; it < 64; ++it) {
        int idx = it * 256 + t;
        float4 v = xp[idx];
        int c = g * 64 + (idx >> 8);
        float sc = gs[c] * rstd;
        float bi = gb[c] - mean * sc;
        ushort4 o;
        o.x = f2bf(v.x * sc + bi); o.y = f2bf(v.y * sc + bi);
        o.z = f2bf(v.z * sc + bi); o.w = f2bf(v.w * sc + bi);
        ((ushort4*)hp)[idx] = o;
    }
}

// ------------- transpose: in[b,512,1024] bf16 -> out[b,1024,512] bf16 -------
__global__ __launch_bounds__(256) void transpose_kernel(const unsigned short* __restrict__ in,
                                                        unsigned short* __restrict__ outp) {
    __shared__ unsigned short tile[64][65];
    int i0 = blockIdx.x * 64;
    int c0 = blockIdx.y * 64;
    size_t bb = (size_t)blockIdx.z * 512 * 1024;
    int t = threadIdx.x;
    int r = t >> 3;
    int col0 = (t & 7) * 8;
#pragma unroll
    for (int p = 0; p < 2; ++p) {
        int row = r + p * 32;
        uint4 v = *(const uint4*)&in[bb + (size_t)(c0 + row) * 1024 + i0 + col0];
        const unsigned short* pv = (const unsigned short*)&v;
#pragma unroll
        for (int j = 0; j < 8; ++j) tile[row][col0 + j] = pv[j];
    }
    __syncthreads();
    size_t ob = (size_t)blockIdx.z * 1024 * 512;
#pragma unroll
    for (int p = 0; p < 2; ++p) {
        int row = r + p * 32;
        unsigned short v[8];
#pragma unroll
        for (int j = 0; j < 8; ++j) v[j] = tile[col0 + j][row];
        *(uint4*)&outp[ob + (size_t)(i0 + row) * 512 + c0 + col0] = *(const uint4*)v;
    }
}

// ------------- weights f32 -> bf16 (4 matrices of 512x512) ------------------
__global__ __launch_bounds__(256) void wcvt_kernel(const float* __restrict__ w0,
                                                   const float* __restrict__ w1,
                                                   const float* __restrict__ w2,
                                                   const float* __restrict__ w3,
                                                   unsigned short* __restrict__ outp) {
    const float* s = (blockIdx.y == 0) ? w0 : (blockIdx.y == 1) ? w1 : (blockIdx.y == 2) ? w2 : w3;
    unsigned short* o = outp + (size_t)blockIdx.y * 262144;
    int idx = blockIdx.x * 256 + threadIdx.x;
    float4 v = ((const float4*)s)[idx];
    ushort4 r;
    r.x = f2bf(v.x); r.y = f2bf(v.y); r.z = f2bf(v.z); r.w = f2bf(v.w);
    ((ushort4*)o)[idx] = r;
}

// ------- staging: global tile (128 rows x 64 k bf16) -> LDS via LDS-DMA -----
// LDS layout: linear rows of 128B; slot s of row r holds global k-slot s^(r&7).
DI void stage_tile(const unsigned short* __restrict__ g, int ldK,
                   unsigned short* lds, int t) {
    int row_in = t >> 3;                        // 0..31
    int kg = (t & 7) ^ (row_in & 7);            // pre-swizzled global slot
    const unsigned short* src = g + (size_t)row_in * ldK + kg * 8;
    unsigned short* dst = lds + ((t >> 6) << 9);  // wave-uniform base (w*1KB)
#pragma unroll
    for (int c = 0; c < 4; ++c) {
        __builtin_amdgcn_global_load_lds(
            (gas_t*)(unsigned long long)(src + (size_t)c * 32 * ldK),
            (las_t*)(unsigned)(unsigned long long)(dst + c * 2048),
            16, 0, 0);
    }
}

DI bf16x8 frag(const unsigned short* lds, int r, int kg) {
    return *(const bf16x8*)((const char*)lds + r * 128 + ((kg ^ (r & 7)) << 4));
}

// ------------- GEMM engine: C[M,N] = A[M,K] * B[N,K]^T ----------------------
// MODE 0: QKV fused. m0<512 -> qT (C^T bf16 +bias b0); m0<1024 -> kT (b1);
//         else vN natural bf16 (+bias b2).
// MODE 1: bf16 C^T write with scale (scores / PV), no bias.
// MODE 2: f32 C^T write + bias[n] (b0) + residual (proj).
template <int MODE>
__global__ __launch_bounds__(256, 2) void gemm_bt(
        const unsigned short* __restrict__ A, const unsigned short* __restrict__ B,
        const float* __restrict__ b0, const float* __restrict__ b1,
        const float* __restrict__ b2,
        void* __restrict__ C0, void* __restrict__ C1, void* __restrict__ C2,
        const float* __restrict__ resid,
        int M, int N, int K, float scale, size_t sA, size_t sB, size_t sC) {
    __shared__ __align__(16) unsigned short As[8192];   // 128 x 64 bf16
    __shared__ __align__(16) unsigned short Bs[8192];
    int bx = blockIdx.x;
    int b = bx & 7;                 // batch fastest -> XCD-resident per batch
    int tile = bx >> 3;
    int nTx = N >> 7;
    int tx = tile % nTx, ty = tile / nTx;
    int m0 = ty << 7, n0 = tx << 7;
    const unsigned short* Ag = A + sA * b + (size_t)m0 * K;
    const unsigned short* Bg = B + sB * b + (size_t)n0 * K;
    int t = threadIdx.x;
    int lane = t & 63, wid = t >> 6;
    int wm = (wid >> 1) * 64, wn = (wid & 1) * 64;
    const int l15 = lane & 15, lks = lane >> 4;

    f32x4 acc[4][4];
#pragma unroll
    for (int i = 0; i < 4; ++i)
#pragma unroll
        for (int j = 0; j < 4; ++j) acc[i][j] = (f32x4){0.f, 0.f, 0.f, 0.f};

    for (int k0 = 0; k0 < K; k0 += 64) {
        stage_tile(Ag + k0, K, As, t);
        stage_tile(Bg + k0, K, Bs, t);
        asm volatile("s_waitcnt vmcnt(0)" ::: "memory");
        __syncthreads();
#pragma unroll
        for (int kk = 0; kk < 2; ++kk) {
            bf16x8 a_[4], b_[4];
#pragma unroll
            for (int m = 0; m < 4; ++m) a_[m] = frag(As, wm + m * 16 + l15, kk * 4 + lks);
#pragma unroll
            for (int n = 0; n < 4; ++n) b_[n] = frag(Bs, wn + n * 16 + l15, kk * 4 + lks);
#pragma unroll
            for (int m = 0; m < 4; ++m)
#pragma unroll
                for (int n = 0; n < 4; ++n)
                    acc[m][n] = __builtin_amdgcn_mfma_f32_16x16x32_bf16(a_[m], b_[n], acc[m][n], 0, 0, 0);
        }
        __syncthreads();
    }

    const int rbase = lks * 4;
    const size_t cb = sC * b;
    if constexpr (MODE == 0) {
        if (m0 < 1024) {
            unsigned short* Ct = (unsigned short*)(m0 < 512 ? C0 : C1) + cb;
            const float* bias = (m0 < 512) ? b0 : b1;
            int moff = (m0 < 512) ? 0 : 512;
#pragma unroll
            for (int m = 0; m < 4; ++m) {
                int mg = m0 - moff + wm + m * 16 + rbase;
                float bv4[4];
#pragma unroll
                for (int j = 0; j < 4; ++j) bv4[j] = bias[mg + j];
#pragma unroll
                for (int n = 0; n < 4; ++n) {
                    int ng = n0 + wn + n * 16 + l15;
                    f32x4 v = acc[m][n];
                    ushort4 o;
                    o.x = f2bf(v[0] + bv4[0]); o.y = f2bf(v[1] + bv4[1]);
                    o.z = f2bf(v[2] + bv4[2]); o.w = f2bf(v[3] + bv4[3]);
                    *(ushort4*)&Ct[(size_t)ng * 512 + mg] = o;
                }
            }
        } else {
            unsigned short* Vb = (unsigned short*)C2 + cb;
#pragma unroll
            for (int m = 0; m < 4; ++m) {
                int mg = m0 - 1024 + wm + m * 16 + rbase;
                float bv4[4];
#pragma unroll
                for (int j = 0; j < 4; ++j) bv4[j] = b2[mg + j];
#pragma unroll
                for (int n = 0; n < 4; ++n) {
                    int ng = n0 + wn + n * 16 + l15;
                    f32x4 v = acc[m][n];
#pragma unroll
                    for (int j = 0; j < 4; ++j)
                        Vb[(size_t)(mg + j) * 1024 + ng] = f2bf(v[j] + bv4[j]);
                }
            }
        }
    } else if constexpr (MODE == 1) {
        unsigned short* Ct = (unsigned short*)C0 + cb;
#pragma unroll
        for (int m = 0; m < 4; ++m) {
            int mg = m0 + wm + m * 16 + rbase;
#pragma unroll
            for (int n = 0; n < 4; ++n) {
                int ng = n0 + wn + n * 16 + l15;
                f32x4 v = acc[m][n];
                ushort4 o;
                o.x = f2bf(v[0] * scale); o.y = f2bf(v[1] * scale);
                o.z = f2bf(v[2] * scale); o.w = f2bf(v[3] * scale);
                *(ushort4*)&Ct[(size_t)ng * M + mg] = o;
            }
        }
    } else {
        float* Cf = (float*)C0 + cb;
#pragma unroll
        for (int m = 0; m < 4; ++m) {
            int mg = m0 + wm + m * 16 + rbase;
#pragma unroll
            for (int n = 0; n < 4; ++n) {
                int ng = n0 + wn + n * 16 + l15;
                float bn = b0[ng];
                f32x4 v = acc[m][n];
                const float* rp = resid + cb + (size_t)ng * M + mg;
                float4 o;
                o.x = v[0] + bn + rp[0]; o.y = v[1] + bn + rp[1];
                o.z = v[2] + bn + rp[2]; o.w = v[3] + bn + rp[3];
                *(float4*)&Cf[(size_t)ng * M + mg] = o;
            }
        }
    }
}

// ------------- row softmax: S[b,1024,1024] bf16 -> P bf16 -------------------
__global__ __launch_bounds__(256) void softmax_kernel(const unsigned short* __restrict__ S,
                                                      unsigned short* __restrict__ P) {
    int bid = blockIdx.x;
    size_t row = ((size_t)(bid & 7) << 10) + (bid >> 3);   // batch-fastest (XCD)
    const ushort4* sp = (const ushort4*)(S + row * 1024);
    int t = threadIdx.x;
    ushort4 u = sp[t];
    float v0 = bf2f(u.x), v1 = bf2f(u.y), v2 = bf2f(u.z), v3 = bf2f(u.w);
    float m = fmaxf(fmaxf(v0, v1), fmaxf(v2, v3));
#pragma unroll
    for (int o = 32; o; o >>= 1) m = fmaxf(m, __shfl_xor(m, o));
    __shared__ float rm[4], rs[4];
    int lane = t & 63, wid = t >> 6;
    if (!lane) rm[wid] = m;
    __syncthreads();
    m = fmaxf(fmaxf(rm[0], rm[1]), fmaxf(rm[2], rm[3]));
    float e0 = __expf(v0 - m), e1 = __expf(v1 - m);
    float e2 = __expf(v2 - m), e3 = __expf(v3 - m);
    float s = (e0 + e1) + (e2 + e3);
#pragma unroll
    for (int o = 32; o; o >>= 1) s += __shfl_xor(s, o);
    if (!lane) rs[wid] = s;
    __syncthreads();
    s = rs[0] + rs[1] + rs[2] + rs[3];
    float inv = 1.f / s;
    ushort4 o4;
    o4.x = f2bf(e0 * inv); o4.y = f2bf(e1 * inv);
    o4.z = f2bf(e2 * inv); o4.w = f2bf(e3 * inv);
    ((ushort4*)(P + row * 1024))[t] = o4;
}

extern "C" void kernel_launch(void* const* d_in, const int* in_sizes, int n_in,
                              void* d_out, int out_size, void* d_ws, size_t ws_size,
                              hipStream_t stream) {
    const float* x  = (const float*)d_in[0];
    const float* gs = (const float*)d_in[1];
    const float* gb = (const float*)d_in[2];
    const float* wq = (const float*)d_in[3];
    const float* bq = (const float*)d_in[4];
    const float* wk = (const float*)d_in[5];
    const float* bk = (const float*)d_in[6];
    const float* wv = (const float*)d_in[7];
    const float* bv = (const float*)d_in[8];
    const float* wp = (const float*)d_in[9];
    const float* bp = (const float*)d_in[10];
    float* out = (float*)d_out;

    char* ws = (char*)d_ws;
    const size_t MB = 1u << 20;
    unsigned short* hT = (unsigned short*)(ws + 0);        // [b][1024][512]
    unsigned short* wb = (unsigned short*)(ws + 8 * MB);   // [wq;wk;wv;wp] bf16
    unsigned short* qT = (unsigned short*)(ws + 10 * MB);  // [b][1024][512]
    unsigned short* kT = (unsigned short*)(ws + 18 * MB);  // [b][1024][512]
    unsigned short* vN = (unsigned short*)(ws + 26 * MB);  // [b][512][1024]
    unsigned short* S  = (unsigned short*)(ws + 34 * MB);  // [b][1024][1024] bf16
    unsigned short* P  = (unsigned short*)(ws + 50 * MB);  // [b][1024][1024] bf16
    unsigned short* OT = (unsigned short*)(ws + 66 * MB);  // [b][1024][512]
    unsigned short* hN = (unsigned short*)(ws + 74 * MB);  // [b][512][1024]

    const unsigned short* wpb = wb + 3 * 262144;
    const size_t sH = 1024 * 512;
    const size_t sS = 1024 * 1024;

    gn_kernel<<<64, 256, 0, stream>>>(x, gs, gb, hN);
    transpose_kernel<<<dim3(16, 8, 8), 256, 0, stream>>>(hN, hT);
    wcvt_kernel<<<dim3(256, 4), 256, 0, stream>>>(wq, wk, wv, wp, wb);

    // QKV fused: A = [Wq;Wk;Wv] (1536x512), B = hT -> qT, kT (C^T), vN (nat)
    gemm_bt<0><<<96 * 8, 256, 0, stream>>>(
        wb, hT, bq, bk, bv, qT, kT, vN, nullptr,
        1536, 1024, 512, 1.f, 0, sH, sH);
    // scores: A=kT, B=qT -> S[i][j] bf16 (C^T write), scaled
    gemm_bt<1><<<64 * 8, 256, 0, stream>>>(
        kT, qT, nullptr, nullptr, nullptr, S, nullptr, nullptr, nullptr,
        1024, 1024, 512, 0.044194173824159216f, sH, sH, sS);
    softmax_kernel<<<8192, 256, 0, stream>>>(S, P);
    // PV: A=vN, B=P -> OT[i][c] (C^T write)
    gemm_bt<1><<<32 * 8, 256, 0, stream>>>(
        vN, P, nullptr, nullptr, nullptr, OT, nullptr, nullptr, nullptr,
        512, 1024, 1024, 1.f, sH, sS, sH);
    // proj: A=OT, B=Wp -> out[b][c][i] f32 (C^T write) + bias[c] + residual
    gemm_bt<2><<<32 * 8, 256, 0, stream>>>(
        OT, wpb, bp, nullptr, nullptr, out, nullptr, nullptr, x,
        1024, 512, 512, 1.f, sH, 0, (size_t)512 * 1024);
}

// Round 3
// 81.247 us; speedup vs baseline: 1.8318x; 1.2818x over previous
//
#include <hip/hip_runtime.h>
#include <hip/hip_bf16.h>

#define DI __device__ __forceinline__

typedef __bf16 bf16x8 __attribute__((ext_vector_type(8)));
typedef float f32x4 __attribute__((ext_vector_type(4)));

typedef const void __attribute__((address_space(1))) gas_t;
typedef void __attribute__((address_space(3))) las_t;

DI unsigned short f2bf(float f) {
    unsigned u = __builtin_bit_cast(unsigned, f);
    u += 0x7fffu + ((u >> 16) & 1u);   // RNE
    return (unsigned short)(u >> 16);
}

// ---------------- prep: GN stats (512 blocks) + weight cvt (1024 blocks) ----
__global__ __launch_bounds__(256) void prep_kernel(const float* __restrict__ x,
                                                   float2* __restrict__ part,
                                                   const float* __restrict__ w0,
                                                   const float* __restrict__ w1,
                                                   const float* __restrict__ w2,
                                                   const float* __restrict__ w3,
                                                   unsigned short* __restrict__ wb) {
    int bx = blockIdx.x;
    int t = threadIdx.x;
    if (bx < 512) {
        // stats: block = (b,g,ch): 8 channels x 1024 px
        size_t base = (size_t)bx * 8 * 1024;
        const float4* xp = (const float4*)(x + base);
        float s = 0.f, q = 0.f;
#pragma unroll
        for (int it = 0; it < 8; ++it) {
            float4 v = xp[it * 256 + t];
            s += (v.x + v.y) + (v.z + v.w);
            q += (v.x * v.x + v.y * v.y) + (v.z * v.z + v.w * v.w);
        }
#pragma unroll
        for (int o = 32; o; o >>= 1) { s += __shfl_xor(s, o); q += __shfl_xor(q, o); }
        __shared__ float rs[4], rq[4];
        int lane = t & 63, wid = t >> 6;
        if (!lane) { rs[wid] = s; rq[wid] = q; }
        __syncthreads();
        if (t == 0)
            part[bx] = make_float2(rs[0] + rs[1] + rs[2] + rs[3],
                                   rq[0] + rq[1] + rq[2] + rq[3]);
    } else {
        int idx4 = bx - 512;                 // 0..1023
        int w = idx4 >> 8;
        const float* s = (w == 0) ? w0 : (w == 1) ? w1 : (w == 2) ? w2 : w3;
        unsigned short* o = wb + (size_t)w * 262144;
        int idx = (idx4 & 255) * 256 + t;
        float4 v = ((const float4*)s)[idx];
        ushort4 r;
        r.x = f2bf(v.x); r.y = f2bf(v.y); r.z = f2bf(v.z); r.w = f2bf(v.w);
        ((ushort4*)o)[idx] = r;
    }
}

// -------- GN apply + transposed write: x[b,c,hw] f32 -> hT[b,hw,c] bf16 -----
__global__ __launch_bounds__(256) void gn_applyT(const float* __restrict__ x,
                                                 const float2* __restrict__ part,
                                                 const float* __restrict__ gs,
                                                 const float* __restrict__ gb,
                                                 unsigned short* __restrict__ hT) {
    int bg = blockIdx.x >> 3, ic = blockIdx.x & 7;
    int b = bg >> 3, g = bg & 7;
    float s = 0.f, q = 0.f;
#pragma unroll
    for (int k = 0; k < 8; ++k) { float2 p = part[bg * 8 + k]; s += p.x; q += p.y; }
    float mean = s * (1.f / 65536.f);
    float var = q * (1.f / 65536.f) - mean * mean;
    float rstd = rsqrtf(var + 1e-5f);

    __shared__ unsigned short tile[128 * 66];   // [i][c], stride 66
    int t = threadIdx.x;
    int i4 = t & 31, cq = t >> 5;
    size_t xbase = ((size_t)b * 512 + g * 64) * 1024 + ic * 128;
#pragma unroll
    for (int pass = 0; pass < 8; ++pass) {
        int c = pass * 8 + cq;
        float4 v = *(const float4*)&x[xbase + (size_t)c * 1024 + i4 * 4];
        int gc = g * 64 + c;
        float sc = gs[gc] * rstd, bi = gb[gc] - mean * sc;
        unsigned short* tp = &tile[(i4 * 4) * 66 + c];
        tp[0]   = f2bf(v.x * sc + bi);
        tp[66]  = f2bf(v.y * sc + bi);
        tp[132] = f2bf(v.z * sc + bi);
        tp[198] = f2bf(v.w * sc + bi);
    }
    __syncthreads();
    int i = t >> 1, h = t & 1;
    const unsigned short* tp2 = &tile[i * 66 + h * 32];
    unsigned short* op = &hT[(size_t)b * (1024 * 512) + (size_t)(ic * 128 + i) * 512 + g * 64 + h * 32];
#pragma unroll
    for (int cc = 0; cc < 4; ++cc) {
        unsigned short tmp[8];
#pragma unroll
        for (int j = 0; j < 8; ++j) tmp[j] = tp2[cc * 8 + j];
        *(uint4*)&op[cc * 8] = *(const uint4*)tmp;
    }
}

// ------- staging: global tile (ROWS x 64 k bf16) -> LDS via LDS-DMA ---------
// LDS: linear rows of 128B; slot s of row r holds global k-slot s^(r&7).
template <int ROWS>
DI void stage_tile(const unsigned short* __restrict__ g, int ldK,
                   unsigned short* lds, int t) {
    int row_in = t >> 3;                        // 0..31
    int kg = (t & 7) ^ (row_in & 7);            // pre-swizzled global slot
    const unsigned short* src = g + (size_t)row_in * ldK + kg * 8;
    unsigned short* dst = lds + ((t >> 6) << 9);  // wave-uniform base
#pragma unroll
    for (int c = 0; c < ROWS / 32; ++c) {
        __builtin_amdgcn_global_load_lds(
            (gas_t*)(unsigned long long)(src + (size_t)c * 32 * ldK),
            (las_t*)(unsigned)(unsigned long long)(dst + c * 2048),
            16, 0, 0);
    }
}

DI bf16x8 frag(const unsigned short* lds, int r, int kg) {
    return *(const bf16x8*)((const char*)lds + r * 128 + ((kg ^ (r & 7)) << 4));
}

// ------------- GEMM engine: C[M,N] = A[M,K] * B[N,K]^T, tile TM x 128 -------
// MODE 0: QKV fused (TM=128): m0<512 -> qT C^T(+b0); <1024 -> kT(+b1); else vN nat(+b2)
// MODE 1: scores -> E = exp(acc*scale) bf16 C^T + partial row sums to spart
// MODE 2: PV -> bf16 C^T, scaled by 1/rowsum (from spart)
// MODE 3: proj -> f32 C^T + bias[ng] + residual
template <int TM, int MODE, int MINW>
__global__ __launch_bounds__(256, MINW) void gemm_bt(
        const unsigned short* __restrict__ A, const unsigned short* __restrict__ B,
        const float* __restrict__ b0, const float* __restrict__ b1,
        const float* __restrict__ b2,
        void* __restrict__ C0, void* __restrict__ C1, void* __restrict__ C2,
        const float* __restrict__ resid, float* __restrict__ spart,
        int M, int N, int K, float scale, size_t sA, size_t sB, size_t sC) {
    constexpr int MR = TM / 32;                       // per-wave m-fragments
    __shared__ __align__(16) unsigned short As[TM * 64];
    __shared__ __align__(16) unsigned short Bs[128 * 64];
    int bx = blockIdx.x;
    int b = bx & 7;                 // batch fastest -> XCD-resident per batch
    int tile = bx >> 3;
    int nTx = N >> 7;
    int tx = tile % nTx, ty = tile / nTx;
    int m0 = ty * TM, n0 = tx << 7;
    const unsigned short* Ag = A + sA * b + (size_t)m0 * K;
    const unsigned short* Bg = B + sB * b + (size_t)n0 * K;
    int t = threadIdx.x;
    int lane = t & 63, wid = t >> 6;
    int wm = (wid >> 1) * (TM / 2), wn = (wid & 1) * 64;
    const int l15 = lane & 15, lks = lane >> 4;

    f32x4 acc[MR][4];
#pragma unroll
    for (int i = 0; i < MR; ++i)
#pragma unroll
        for (int j = 0; j < 4; ++j) acc[i][j] = (f32x4){0.f, 0.f, 0.f, 0.f};

    for (int k0 = 0; k0 < K; k0 += 64) {
        stage_tile<TM>(Ag + k0, K, As, t);
        stage_tile<128>(Bg + k0, K, Bs, t);
        asm volatile("s_waitcnt vmcnt(0)" ::: "memory");
        __syncthreads();
#pragma unroll
        for (int kk = 0; kk < 2; ++kk) {
            bf16x8 a_[MR], b_[4];
#pragma unroll
            for (int m = 0; m < MR; ++m) a_[m] = frag(As, wm + m * 16 + l15, kk * 4 + lks);
#pragma unroll
            for (int n = 0; n < 4; ++n) b_[n] = frag(Bs, wn + n * 16 + l15, kk * 4 + lks);
#pragma unroll
            for (int m = 0; m < MR; ++m)
#pragma unroll
                for (int n = 0; n < 4; ++n)
                    acc[m][n] = __builtin_amdgcn_mfma_f32_16x16x32_bf16(a_[m], b_[n], acc[m][n], 0, 0, 0);
        }
        __syncthreads();
    }

    const int rbase = lks * 4;
    const size_t cb = sC * b;
    if constexpr (MODE == 0) {
        if (m0 < 1024) {
            unsigned short* Ct = (unsigned short*)(m0 < 512 ? C0 : C1) + cb;
            const float* bias = (m0 < 512) ? b0 : b1;
            int moff = (m0 < 512) ? 0 : 512;
#pragma unroll
            for (int m = 0; m < MR; ++m) {
                int mg = m0 - moff + wm + m * 16 + rbase;
                float bv4[4];
#pragma unroll
                for (int j = 0; j < 4; ++j) bv4[j] = bias[mg + j];
#pragma unroll
                for (int n = 0; n < 4; ++n) {
                    int ng = n0 + wn + n * 16 + l15;
                    f32x4 v = acc[m][n];
                    ushort4 o;
                    o.x = f2bf(v[0] + bv4[0]); o.y = f2bf(v[1] + bv4[1]);
                    o.z = f2bf(v[2] + bv4[2]); o.w = f2bf(v[3] + bv4[3]);
                    *(ushort4*)&Ct[(size_t)ng * 512 + mg] = o;
                }
            }
        } else {
            unsigned short* Vb = (unsigned short*)C2 + cb;
#pragma unroll
            for (int m = 0; m < MR; ++m) {
                int mg = m0 - 1024 + wm + m * 16 + rbase;
                float bv4[4];
#pragma unroll
                for (int j = 0; j < 4; ++j) bv4[j] = b2[mg + j];
#pragma unroll
                for (int n = 0; n < 4; ++n) {
                    int ng = n0 + wn + n * 16 + l15;
                    f32x4 v = acc[m][n];
#pragma unroll
                    for (int j = 0; j < 4; ++j)
                        Vb[(size_t)(mg + j) * 1024 + ng] = f2bf(v[j] + bv4[j]);
                }
            }
        }
    } else if constexpr (MODE == 1) {
        unsigned short* Ct = (unsigned short*)C0 + cb;
        float psum[4] = {0.f, 0.f, 0.f, 0.f};
#pragma unroll
        for (int m = 0; m < MR; ++m) {
            int mg = m0 + wm + m * 16 + rbase;
#pragma unroll
            for (int n = 0; n < 4; ++n) {
                int ng = n0 + wn + n * 16 + l15;
                f32x4 v = acc[m][n];
                float e0 = __expf(v[0] * scale), e1 = __expf(v[1] * scale);
                float e2 = __expf(v[2] * scale), e3 = __expf(v[3] * scale);
                psum[n] += (e0 + e1) + (e2 + e3);
                ushort4 o;
                o.x = f2bf(e0); o.y = f2bf(e1); o.z = f2bf(e2); o.w = f2bf(e3);
                *(ushort4*)&Ct[(size_t)ng * M + mg] = o;
            }
        }
        int rb = (m0 >> 7) * 2 + (wid >> 1);
#pragma unroll
        for (int n = 0; n < 4; ++n) {
            float p = psum[n];
            p += __shfl_xor(p, 16);
            p += __shfl_xor(p, 32);
            if (lks == 0) {
                int ng = n0 + wn + n * 16 + l15;
                spart[(size_t)(b * 16 + rb) * 1024 + ng] = p;
            }
        }
    } else if constexpr (MODE == 2) {
        unsigned short* Ct = (unsigned short*)C0 + cb;
        float inv[4];
#pragma unroll
        for (int n = 0; n < 4; ++n) {
            int ng = n0 + wn + n * 16 + l15;
            float ssum = 0.f;
#pragma unroll
            for (int k = 0; k < 16; ++k) ssum += spart[(size_t)(b * 16 + k) * 1024 + ng];
            inv[n] = 1.f / ssum;
        }
#pragma unroll
        for (int m = 0; m < MR; ++m) {
            int mg = m0 + wm + m * 16 + rbase;
#pragma unroll
            for (int n = 0; n < 4; ++n) {
                int ng = n0 + wn + n * 16 + l15;
                f32x4 v = acc[m][n];
                ushort4 o;
                o.x = f2bf(v[0] * inv[n]); o.y = f2bf(v[1] * inv[n]);
                o.z = f2bf(v[2] * inv[n]); o.w = f2bf(v[3] * inv[n]);
                *(ushort4*)&Ct[(size_t)ng * M + mg] = o;
            }
        }
    } else {
        float* Cf = (float*)C0 + cb;
#pragma unroll
        for (int m = 0; m < MR; ++m) {
            int mg = m0 + wm + m * 16 + rbase;
#pragma unroll
            for (int n = 0; n < 4; ++n) {
                int ng = n0 + wn + n * 16 + l15;
                float bn = b0[ng];
                f32x4 v = acc[m][n];
                const float* rp = resid + cb + (size_t)ng * M + mg;
                float4 o;
                o.x = v[0] + bn + rp[0]; o.y = v[1] + bn + rp[1];
                o.z = v[2] + bn + rp[2]; o.w = v[3] + bn + rp[3];
                *(float4*)&Cf[(size_t)ng * M + mg] = o;
            }
        }
    }
}

extern "C" void kernel_launch(void* const* d_in, const int* in_sizes, int n_in,
                              void* d_out, int out_size, void* d_ws, size_t ws_size,
                              hipStream_t stream) {
    const float* x  = (const float*)d_in[0];
    const float* gs = (const float*)d_in[1];
    const float* gb = (const float*)d_in[2];
    const float* wq = (const float*)d_in[3];
    const float* bq = (const float*)d_in[4];
    const float* wk = (const float*)d_in[5];
    const float* bk = (const float*)d_in[6];
    const float* wv = (const float*)d_in[7];
    const float* bv = (const float*)d_in[8];
    const float* wp = (const float*)d_in[9];
    const float* bp = (const float*)d_in[10];
    float* out = (float*)d_out;

    char* ws = (char*)d_ws;
    const size_t MB = 1u << 20;
    unsigned short* hT = (unsigned short*)(ws + 0);         // [b][1024][512]
    unsigned short* wb = (unsigned short*)(ws + 8 * MB);    // [wq;wk;wv;wp] bf16
    unsigned short* qT = (unsigned short*)(ws + 10 * MB);   // [b][1024][512]
    unsigned short* kT = (unsigned short*)(ws + 18 * MB);   // [b][1024][512]
    unsigned short* vN = (unsigned short*)(ws + 26 * MB);   // [b][512][1024]
    unsigned short* E  = (unsigned short*)(ws + 34 * MB);   // [b][1024][1024] bf16
    unsigned short* OT = (unsigned short*)(ws + 50 * MB);   // [b][1024][512]
    float2* gnpart     = (float2*)(ws + 58 * MB);           // 512 x float2
    float*  spart      = (float*)(ws + 58 * MB + 65536);    // [b][16][1024] f32

    const unsigned short* wpb = wb + 3 * 262144;
    const size_t sH = 1024 * 512;
    const size_t sS = 1024 * 1024;

    prep_kernel<<<1536, 256, 0, stream>>>(x, gnpart, wq, wk, wv, wp, wb);
    gn_applyT<<<512, 256, 0, stream>>>(x, gnpart, gs, gb, hT);

    // QKV fused: A = [Wq;Wk;Wv] (1536x512), B = hT -> qT, kT (C^T), vN (nat)
    gemm_bt<128, 0, 3><<<96 * 8, 256, 0, stream>>>(
        wb, hT, bq, bk, bv, qT, kT, vN, nullptr, nullptr,
        1536, 1024, 512, 1.f, 0, sH, sH);
    // scores: A=kT, B=qT -> E[i][j] = exp(s*scale) bf16 (C^T) + spart
    gemm_bt<128, 1, 3><<<64 * 8, 256, 0, stream>>>(
        kT, qT, nullptr, nullptr, nullptr, E, nullptr, nullptr, nullptr, spart,
        1024, 1024, 512, 0.044194173824159216f, sH, sH, sS);
    // PV: A=vN, B=E -> OT[i][c] (C^T), normalized by rowsum
    gemm_bt<64, 2, 3><<<64 * 8, 256, 0, stream>>>(
        vN, E, nullptr, nullptr, nullptr, OT, nullptr, nullptr, nullptr, spart,
        512, 1024, 1024, 1.f, sH, sS, sH);
    // proj: A=OT, B=Wp -> out[b][c][i] f32 (C^T) + bias[c] + residual
    gemm_bt<64, 3, 3><<<64 * 8, 256, 0, stream>>>(
        OT, wpb, bp, nullptr, nullptr, out, nullptr, nullptr, x, nullptr,
        1024, 512, 512, 1.f, sH, 0, (size_t)512 * 1024);
}